// Round 8
// baseline (790.586 us; speedup 1.0000x reference)
//
#include <hip/hip_runtime.h>

// ---------------------------------------------------------------------------
// CellVGAE GCN encoder: x -> GCN(512,128)+ReLU -> GCN(128,128)+ReLU
//                         -> {GCN(128,64) mean, GCN(128,64) log_std}
// Round 8:
//  - GEMM reverted to round-5 config (64x128 tile, fragment-order LDS; best
//    measured 66 us) + SPLIT variant for pre-split bf16 A (K=128 layers).
//  - Propagate feature-sliced 8 ways (slice = blockIdx & 7 -> XCD affinity):
//    per-XCD gather working set 25.6 MB -> 3.2 MB (L2-resident). Wave =
//    1 node x 16 feat-lanes x 4 edge-slots, 2-deep unroll, shuffle fold.
// ---------------------------------------------------------------------------

using u16 = unsigned short;
typedef __attribute__((ext_vector_type(8))) short short8;
typedef __attribute__((ext_vector_type(4))) float f32x4;

__device__ __forceinline__ void split_bf16(float f, u16& hi, u16& lo) {
    unsigned b = __float_as_uint(f);
    hi = (u16)(b >> 16);
    float rem = f - __uint_as_float(b & 0xFFFF0000u);
    lo = (u16)(__float_as_uint(rem) >> 16);
}

// Block-wide mode detect: 1 = int64 edge_index, 0 = int32.
__device__ __forceinline__ int block_mode(const int* __restrict__ ew, int* sflag) {
    if (threadIdx.x == 0) *sflag = 0;
    __syncthreads();
    if (ew[2 * (int)threadIdx.x + 1] != 0) atomicOr(sflag, 1);
    __syncthreads();
    return *sflag ? 0 : 1;
}

// ---- merged: weight transposed-splits (blocks 0..383) + degree count ------
#define CONVB 384
__global__ void conv_deg_kernel(const float* __restrict__ W1, const float* __restrict__ W2,
                                const float* __restrict__ Wm, const float* __restrict__ Ws,
                                u16* __restrict__ W1t_hi, u16* __restrict__ W1t_lo,
                                u16* __restrict__ W2t_hi, u16* __restrict__ W2t_lo,
                                u16* __restrict__ Wct_hi, u16* __restrict__ Wct_lo,
                                const int* __restrict__ ew, int* __restrict__ deg, int E) {
    if (blockIdx.x < CONVB) {
        int idx = blockIdx.x * 256 + threadIdx.x;
        u16 h, l;
        if (idx < 65536) {                 // W1: 512x128 -> [128][512]
            int k = idx >> 7, n = idx & 127;
            split_bf16(W1[idx], h, l);
            W1t_hi[n * 512 + k] = h;
            W1t_lo[n * 512 + k] = l;
        } else if (idx < 81920) {          // W2: 128x128 -> [128][128]
            int t = idx - 65536;
            int k = t >> 7, n = t & 127;
            split_bf16(W2[t], h, l);
            W2t_hi[n * 128 + k] = h;
            W2t_lo[n * 128 + k] = l;
        } else if (idx < 98304) {          // [Wm|Ws]: 128x128 -> [128][128]
            int t = idx - 81920;
            int k = t >> 7, j = t & 127;
            float f = (j < 64) ? Wm[k * 64 + j] : Ws[k * 64 + (j - 64)];
            split_bf16(f, h, l);
            Wct_hi[j * 128 + k] = h;
            Wct_lo[j * 128 + k] = l;
        }
    } else {
        __shared__ int sflag;
        int mode = block_mode(ew, &sflag);
        int e = (blockIdx.x - CONVB) * 256 + threadIdx.x;
        if (e >= E) return;
        int d = mode ? ew[2 * E + 2 * e] : ew[E + e];
        atomicAdd(&deg[d], 1);
    }
}

// ---- exclusive scan over deg -> rowptr, fused dis = rsqrt(deg+1) ----------
__global__ void scan_block_kernel(const int* __restrict__ deg, int* __restrict__ rowptr,
                                  int* __restrict__ aux, float* __restrict__ dis, int N) {
    __shared__ int s[256];
    int i = blockIdx.x * 256 + threadIdx.x;
    int v = (i < N) ? deg[i] : 0;
    if (i < N) dis[i] = rsqrtf((float)v + 1.0f);
    s[threadIdx.x] = v;
    __syncthreads();
    for (int off = 1; off < 256; off <<= 1) {
        int t = (threadIdx.x >= off) ? s[threadIdx.x - off] : 0;
        __syncthreads();
        s[threadIdx.x] += t;
        __syncthreads();
    }
    if (i < N) rowptr[i] = s[threadIdx.x] - v;
    if (threadIdx.x == 255) aux[blockIdx.x] = s[255];
}

__global__ void scan_aux_kernel(int* __restrict__ aux, int nb) {
    __shared__ int s[256];
    int i = threadIdx.x;
    int v = (i < nb) ? aux[i] : 0;
    s[i] = v;
    __syncthreads();
    for (int off = 1; off < 256; off <<= 1) {
        int t = (i >= off) ? s[i - off] : 0;
        __syncthreads();
        s[i] += t;
        __syncthreads();
    }
    if (i < nb) aux[i] = s[i] - v;
}

__global__ void add_offsets_kernel(int* __restrict__ rowptr, const int* __restrict__ aux,
                                   int N, int E) {
    int i = blockIdx.x * 256 + threadIdx.x;
    if (i < N) rowptr[i] += aux[i >> 8];
    if (i == 0) rowptr[N] = E;
}

// ---- CSR fill (mode detect inlined) ---------------------------------------
__global__ void fill_csr_kernel(const int* __restrict__ ew,
                                const int* __restrict__ rowptr, int* __restrict__ cursor,
                                int* __restrict__ csr_src, int E) {
    __shared__ int sflag;
    int mode = block_mode(ew, &sflag);
    int e = blockIdx.x * blockDim.x + threadIdx.x;
    if (e >= E) return;
    int s = mode ? ew[2 * e] : ew[e];
    int d = mode ? ew[2 * E + 2 * e] : ew[E + e];
    int pos = rowptr[d] + atomicAdd(&cursor[d], 1);
    csr_src[pos] = s;
}

// ---- MFMA GEMM (round-5 config): C[N x 128] = A[N x K] @ B[K x 128] -------
// Block 64 rows x 128 cols, 4 waves each 32x64 (2x4 MFMA tiles).
// Fragment-order LDS: tile t at t*520 u16, lane L's 16B frag at +L*8.
// SPLIT=false: A f32, split in-register. SPLIT=true: A pre-split hi/lo u16.
#define TILE_OFF(t) ((t) * 520)

template <int K, bool SPLIT>
__global__ __launch_bounds__(256) void gemm_mfma(
    const float* __restrict__ A,
    const u16* __restrict__ Ahi, const u16* __restrict__ Alo,
    const u16* __restrict__ Bh, const u16* __restrict__ Bl,
    float* __restrict__ C, int N) {
    __shared__ u16 AsH[4 * 520], AsL[4 * 520];   // 64 rows
    __shared__ u16 BsH[8 * 520], BsL[8 * 520];   // 128 cols

    const int tid = threadIdx.x;
    const int w = tid >> 6, lane = tid & 63;
    const int row0 = blockIdx.x * 64;

    // A staging: wave w stages rows w*16..+15; lane -> (row15, k-chunk)
    const int s_ar = w * 16 + (lane & 15);
    const int s_ak = (lane >> 4) * 8;
    const int a_dst = TILE_OFF(w) + lane * 8;
    // B staging: thread -> (col, k-half)
    const int s_bc = tid >> 1;
    const int s_bk = (tid & 1) * 16;
    const int b_q0 = (tid & 1) * 2;
    const int b_dst0 = TILE_OFF(s_bc >> 4) + ((s_bc & 15) + 16 * (b_q0 + 0)) * 8;
    const int b_dst1 = TILE_OFF(s_bc >> 4) + ((s_bc & 15) + 16 * (b_q0 + 1)) * 8;

    // compute: wave tile = 32 rows x 64 cols
    const int R = (w >> 1) * 32, Cc = (w & 1) * 64;
    const int atile = (w >> 1) * 2;
    const int btile = (w & 1) * 4;
    const int m16 = lane & 15, quad = lane >> 4;

    f32x4 acc[2][4];
#pragma unroll
    for (int i = 0; i < 2; ++i)
#pragma unroll
        for (int j = 0; j < 4; ++j) acc[i][j] = (f32x4)0.f;

    int grow = row0 + s_ar;
    const bool ok = (grow < N);
    if (grow > N - 1) grow = N - 1;
    const float* aptr;
    const u16 *ahp, *alp;
    if constexpr (SPLIT) {
        ahp = Ahi + (size_t)grow * K + s_ak;
        alp = Alo + (size_t)grow * K + s_ak;
    } else {
        aptr = A + (size_t)grow * K + s_ak;
    }
    const u16* bph = Bh + (size_t)s_bc * K + s_bk;
    const u16* bpl = Bl + (size_t)s_bc * K + s_bk;

    float av[8];
    short8 pah, pal;
    short8 rbh0, rbh1, rbl0, rbl1;
    {
        if constexpr (SPLIT) {
            pah = *(const short8*)&ahp[0];
            pal = *(const short8*)&alp[0];
        } else {
            f32x4 v0 = (f32x4)0.f, v1 = (f32x4)0.f;
            if (ok) { v0 = *(const f32x4*)&aptr[0]; v1 = *(const f32x4*)&aptr[4]; }
#pragma unroll
            for (int q = 0; q < 4; ++q) { av[q] = v0[q]; av[4 + q] = v1[q]; }
        }
        rbh0 = *(const short8*)&bph[0];
        rbh1 = *(const short8*)&bph[8];
        rbl0 = *(const short8*)&bpl[0];
        rbl1 = *(const short8*)&bpl[8];
    }

    const int ksteps = K >> 5;
    for (int ks = 0; ks < ksteps; ++ks) {
        short8 ah, al;
        if constexpr (SPLIT) {
            ah = pah; al = pal;
        } else {
#pragma unroll
            for (int q = 0; q < 8; ++q) {
                u16 h, l;
                split_bf16(av[q], h, l);
                ah[q] = (short)h;
                al[q] = (short)l;
            }
        }
        __syncthreads();
        *(short8*)&AsH[a_dst] = ah;
        *(short8*)&AsL[a_dst] = al;
        *(short8*)&BsH[b_dst0] = rbh0;
        *(short8*)&BsH[b_dst1] = rbh1;
        *(short8*)&BsL[b_dst0] = rbl0;
        *(short8*)&BsL[b_dst1] = rbl1;
        __syncthreads();

        if (ks + 1 < ksteps) {
            const int k0 = (ks + 1) * 32;
            if constexpr (SPLIT) {
                pah = *(const short8*)&ahp[k0];
                pal = *(const short8*)&alp[k0];
            } else {
                f32x4 v0 = (f32x4)0.f, v1 = (f32x4)0.f;
                if (ok) { v0 = *(const f32x4*)&aptr[k0]; v1 = *(const f32x4*)&aptr[k0 + 4]; }
#pragma unroll
                for (int q = 0; q < 4; ++q) { av[q] = v0[q]; av[4 + q] = v1[q]; }
            }
            rbh0 = *(const short8*)&bph[k0];
            rbh1 = *(const short8*)&bph[k0 + 8];
            rbl0 = *(const short8*)&bpl[k0];
            rbl1 = *(const short8*)&bpl[k0 + 8];
        }

        short8 fa_h[2], fa_l[2], fb_h[4], fb_l[4];
#pragma unroll
        for (int i = 0; i < 2; ++i) {
            fa_h[i] = *(const short8*)&AsH[TILE_OFF(atile + i) + lane * 8];
            fa_l[i] = *(const short8*)&AsL[TILE_OFF(atile + i) + lane * 8];
        }
#pragma unroll
        for (int j = 0; j < 4; ++j) {
            fb_h[j] = *(const short8*)&BsH[TILE_OFF(btile + j) + lane * 8];
            fb_l[j] = *(const short8*)&BsL[TILE_OFF(btile + j) + lane * 8];
        }
#pragma unroll
        for (int i = 0; i < 2; ++i)
#pragma unroll
            for (int j = 0; j < 4; ++j) {
                acc[i][j] = __builtin_amdgcn_mfma_f32_16x16x32_bf16(
                    fa_h[i], fb_h[j], acc[i][j], 0, 0, 0);
                acc[i][j] = __builtin_amdgcn_mfma_f32_16x16x32_bf16(
                    fa_h[i], fb_l[j], acc[i][j], 0, 0, 0);
                acc[i][j] = __builtin_amdgcn_mfma_f32_16x16x32_bf16(
                    fa_l[i], fb_h[j], acc[i][j], 0, 0, 0);
            }
    }

    // epilogue: C/D layout col=lane&15, row=quad*4+reg
#pragma unroll
    for (int i = 0; i < 2; ++i) {
#pragma unroll
        for (int r = 0; r < 4; ++r) {
            int gr = row0 + R + i * 16 + quad * 4 + r;
            if (gr < N) {
#pragma unroll
                for (int j = 0; j < 4; ++j)
                    C[(size_t)gr * 128 + Cc + j * 16 + m16] = acc[i][j][r];
            }
        }
    }
}

// ---- feature-sliced propagate: slice = blockIdx & 7 (XCD affinity) --------
// Wave = 1 node: 16 feat-lanes x 4 edge-slots; 2-deep unroll => 8 gathers
// in flight. Fold over edge slots via shfl. Output split bf16 hi/lo.
__global__ __launch_bounds__(256) void propagate_kernel(
    const float* __restrict__ h, const int* __restrict__ rowptr,
    const int* __restrict__ csr_src, const float* __restrict__ dis,
    const float* __restrict__ bias, u16* __restrict__ out_hi,
    u16* __restrict__ out_lo, int N) {
    const int slice = blockIdx.x & 7;
    const int wave = threadIdx.x >> 6;
    const int v = (blockIdx.x >> 3) * 4 + wave;
    if (v >= N) return;
    const int lane = threadIdx.x & 63;
    const int g = lane >> 4;          // edge slot
    const int f = slice * 16 + (lane & 15);
    const float dv = dis[v];
    const int beg = rowptr[v], end = rowptr[v + 1];
    float acc = 0.f;
    int i = beg + g;
    for (; i + 4 < end; i += 8) {
        int s0 = csr_src[i];
        int s1 = csr_src[i + 4];
        float w0 = dis[s0];
        float w1 = dis[s1];
        float g0 = h[(size_t)s0 * 128 + f];
        float g1 = h[(size_t)s1 * 128 + f];
        acc += w0 * g0;
        acc += w1 * g1;
    }
    if (i < end) {
        int s0 = csr_src[i];
        acc += dis[s0] * h[(size_t)s0 * 128 + f];
    }
    acc += __shfl_down(acc, 32);
    acc += __shfl_down(acc, 16);
    if (g == 0) {
        acc *= dv;
        acc += dv * dv * h[(size_t)v * 128 + f];
        acc += bias[f];
        acc = fmaxf(acc, 0.f);
        u16 hi, lo;
        split_bf16(acc, hi, lo);
        out_hi[(size_t)v * 128 + f] = hi;
        out_lo[(size_t)v * 128 + f] = lo;
    }
}

// ---- feature-sliced final propagate: z_mean / z_log_std (f32 out) ---------
__global__ __launch_bounds__(256) void propagate_final_kernel(
    const float* __restrict__ h, const int* __restrict__ rowptr,
    const int* __restrict__ csr_src, const float* __restrict__ dis,
    const float* __restrict__ bm, const float* __restrict__ bs,
    float* __restrict__ out, int N) {
    const int slice = blockIdx.x & 7;
    const int wave = threadIdx.x >> 6;
    const int v = (blockIdx.x >> 3) * 4 + wave;
    if (v >= N) return;
    const int lane = threadIdx.x & 63;
    const int g = lane >> 4;
    const int f = slice * 16 + (lane & 15);
    const float dv = dis[v];
    const int beg = rowptr[v], end = rowptr[v + 1];
    float acc = 0.f;
    int i = beg + g;
    for (; i + 4 < end; i += 8) {
        int s0 = csr_src[i];
        int s1 = csr_src[i + 4];
        float w0 = dis[s0];
        float w1 = dis[s1];
        float g0 = h[(size_t)s0 * 128 + f];
        float g1 = h[(size_t)s1 * 128 + f];
        acc += w0 * g0;
        acc += w1 * g1;
    }
    if (i < end) {
        int s0 = csr_src[i];
        acc += dis[s0] * h[(size_t)s0 * 128 + f];
    }
    acc += __shfl_down(acc, 32);
    acc += __shfl_down(acc, 16);
    if (g == 0) {
        acc *= dv;
        acc += dv * dv * h[(size_t)v * 128 + f];
        if (f < 64)
            out[(size_t)v * 64 + f] = acc + bm[f];
        else
            out[(size_t)N * 64 + (size_t)v * 64 + (f - 64)] = acc + bs[f - 64];
    }
}

extern "C" void kernel_launch(void* const* d_in, const int* in_sizes, int n_in,
                              void* d_out, int out_size, void* d_ws, size_t ws_size,
                              hipStream_t stream) {
    const float* x  = (const float*)d_in[0];
    const int*   ew = (const int*)d_in[1];
    const float* W1 = (const float*)d_in[2];
    const float* b1 = (const float*)d_in[3];
    const float* W2 = (const float*)d_in[4];
    const float* b2 = (const float*)d_in[5];
    const float* Wm = (const float*)d_in[6];
    const float* bm = (const float*)d_in[7];
    const float* Ws = (const float*)d_in[8];
    const float* bs = (const float*)d_in[9];
    float* out = (float*)d_out;

    const int IN = 512, H = 128;
    const int N = in_sizes[0] / IN;     // 50000
    const int E = in_sizes[1] / 2;      // 800000

    // ---- workspace: ~55.6 MB total (< proven-safe 58.47 MB) ----------------
    char* base = (char*)d_ws;
    size_t off = 0;
    auto alloc = [&](size_t bytes) -> char* {
        char* p = base + off;
        off = (off + bytes + 255) & ~(size_t)255;
        return p;
    };
    char*  degcur  = (char*) alloc(400384);             // deg + cursor (zeroed)
    float* dis     = (float*)alloc((size_t)N * 4);
    int*   rowptr  = (int*)  alloc((size_t)(N + 1) * 4);
    int*   aux     = (int*)  alloc(256 * 4);
    int*   csr_src = (int*)  alloc((size_t)E * 4);
    u16*   W1t_hi  = (u16*)  alloc((size_t)IN * H * 2);
    u16*   W1t_lo  = (u16*)  alloc((size_t)IN * H * 2);
    u16*   W2t_hi  = (u16*)  alloc((size_t)H * H * 2);
    u16*   W2t_lo  = (u16*)  alloc((size_t)H * H * 2);
    u16*   Wct_hi  = (u16*)  alloc((size_t)H * H * 2);
    u16*   Wct_lo  = (u16*)  alloc((size_t)H * H * 2);
    float* hA      = (float*)alloc((size_t)N * H * 4);  // GEMM outputs (f32)
    u16*   hBhi    = (u16*)  alloc((size_t)N * H * 2);  // propagate out hi
    u16*   hBlo    = (u16*)  alloc((size_t)N * H * 2);  // propagate out lo
    (void)ws_size; (void)n_in; (void)out_size;

    int* deg    = (int*)degcur;
    int* cursor = (int*)(degcur + 200192);

    hipMemsetAsync(degcur, 0, 400384, stream);

    const int eblocks = (E + 255) / 256;
    const int nblocks = (N + 255) / 256;

    conv_deg_kernel<<<CONVB + eblocks, 256, 0, stream>>>(
        W1, W2, Wm, Ws, W1t_hi, W1t_lo, W2t_hi, W2t_lo, Wct_hi, Wct_lo,
        ew, deg, E);
    scan_block_kernel<<<nblocks, 256, 0, stream>>>(deg, rowptr, aux, dis, N);
    scan_aux_kernel<<<1, 256, 0, stream>>>(aux, nblocks);
    add_offsets_kernel<<<nblocks, 256, 0, stream>>>(rowptr, aux, N, E);
    fill_csr_kernel<<<eblocks, 256, 0, stream>>>(ew, rowptr, cursor, csr_src, E);

    const int gblocks = (N + 63) / 64;          // 782
    const int pblocks = ((N + 3) / 4) * 8;      // 100000 (4 nodes/block, 8 slices)

    gemm_mfma<512, false><<<gblocks, 256, 0, stream>>>(
        x, nullptr, nullptr, W1t_hi, W1t_lo, hA, N);
    propagate_kernel<<<pblocks, 256, 0, stream>>>(hA, rowptr, csr_src, dis,
                                                  b1, hBhi, hBlo, N);
    gemm_mfma<128, true><<<gblocks, 256, 0, stream>>>(
        nullptr, hBhi, hBlo, W2t_hi, W2t_lo, hA, N);
    propagate_kernel<<<pblocks, 256, 0, stream>>>(hA, rowptr, csr_src, dis,
                                                  b2, hBhi, hBlo, N);
    gemm_mfma<128, true><<<gblocks, 256, 0, stream>>>(
        nullptr, hBhi, hBlo, Wct_hi, Wct_lo, hA, N);
    propagate_final_kernel<<<pblocks, 256, 0, stream>>>(hA, rowptr, csr_src, dis,
                                                        bm, bs, out, N);
}